// Round 1
// baseline (72.071 us; speedup 1.0000x reference)
//
#include <hip/hip_runtime.h>

namespace {
constexpr int kB = 256;
constexpr int kT = 336;
constexpr int kC = 512;
constexpr int kK = 3;
constexpr int kUnroll = 8;   // 336 % 8 == 0
}

// One thread per (b, c) pair. Sequential scan over t with running products:
//   apow = a^t   (for the weight a^t * (1-a))
//   vinv = a^-t  (inv-divisor; min(vinv, 1e8) == 1/max(a^t, 1e-8))
// x loads for the next 8-t chunk are double-buffered in registers so HBM
// latency hides under the dependent accumulate chain.
__global__ __launch_bounds__(256) void ema_mix_kernel(
    const float* __restrict__ x,
    const float* __restrict__ logit_alpha,
    const float* __restrict__ mix_logits,
    float* __restrict__ out)
{
    const int c = ((blockIdx.x & 1) << 8) | threadIdx.x;
    const int b = blockIdx.x >> 1;

    // ---- per-(k,c) parameters (once per thread) ----
    float a[kK], oma[kK], inva[kK], mixw[kK];
    {
        float logits[kK];
        float lmax = -3.402823e38f;
        #pragma unroll
        for (int k = 0; k < kK; ++k) {
            logits[k] = mix_logits[c * kK + k];
            lmax = fmaxf(lmax, logits[k]);
        }
        float esum = 0.f;
        #pragma unroll
        for (int k = 0; k < kK; ++k) {
            logits[k] = expf(logits[k] - lmax);
            esum += logits[k];
        }
        const float rs = 1.0f / esum;
        #pragma unroll
        for (int k = 0; k < kK; ++k) {
            mixw[k] = logits[k] * rs;
            const float z = logit_alpha[k * kC + c];
            float s;
            if (z >= 0.f) {
                s = 1.0f / (1.0f + expf(-z));
            } else {
                const float e = expf(z);
                s = e / (1.0f + e);
            }
            s = fminf(fmaxf(s, 1e-4f), (float)(1.0 - 1e-4));
            a[k]    = s;
            oma[k]  = 1.0f - s;
            inva[k] = 1.0f / s;
        }
    }

    const float* xp = x   + (size_t)b * (kT * kC) + c;
    float*       op = out + (size_t)b * (kT * kC) + c;

    float apow[kK], vinv[kK], S[kK];
    #pragma unroll
    for (int k = 0; k < kK; ++k) { apow[k] = 1.f; vinv[k] = 1.f; S[k] = 0.f; }

    // prologue: stage first chunk
    float xcur[kUnroll];
    #pragma unroll
    for (int i = 0; i < kUnroll; ++i) xcur[i] = xp[i * kC];

    for (int tc = 0; tc < kT; tc += kUnroll) {
        const bool more = (tc + kUnroll < kT);
        float xnxt[kUnroll];
        if (more) {
            #pragma unroll
            for (int i = 0; i < kUnroll; ++i) xnxt[i] = xp[(tc + kUnroll + i) * kC];
        }
        #pragma unroll
        for (int i = 0; i < kUnroll; ++i) {
            const int t = tc + i;
            const float xv = xcur[i];
            float o = 0.f;
            #pragma unroll
            for (int k = 0; k < kK; ++k) {
                const float w = (t == 0) ? 1.0f : apow[k] * oma[k];
                S[k] = fmaf(xv, w, S[k]);
                const float inv = fminf(vinv[k], 1e8f);
                o = fmaf(S[k] * mixw[k], inv, o);
                apow[k] *= a[k];
                vinv[k] *= inva[k];
            }
            op[t * kC] = o;
        }
        if (more) {
            #pragma unroll
            for (int i = 0; i < kUnroll; ++i) xcur[i] = xnxt[i];
        }
    }
}

extern "C" void kernel_launch(void* const* d_in, const int* in_sizes, int n_in,
                              void* d_out, int out_size, void* d_ws, size_t ws_size,
                              hipStream_t stream) {
    const float* x  = (const float*)d_in[0];
    const float* la = (const float*)d_in[1];
    const float* ml = (const float*)d_in[2];
    float* o = (float*)d_out;

    const int blocks = kB * (kC / 256);  // 512 blocks x 256 threads = one thread per (b,c)
    ema_mix_kernel<<<dim3(blocks), dim3(256), 0, stream>>>(x, la, ml, o);
}